// Round 4
// baseline (378.447 us; speedup 1.0000x reference)
//
#include <hip/hip_runtime.h>

// Problem constants (fixed by reference)
#define NN   20000
#define RR   11
#define BB   8
#define IND  300
#define OUTD 256
#define EE   640000
#define RN   (RR * NN)      // 220000 buckets, key = rel*N + src
#define KP   304            // K padded to 19 * 16 for 32x32x16 MFMA
#define KPU  152            // uints per padded row (feat2 and wt)
#define SBS  316            // sbf ushort stride: 632B rows -> 2-way banks (free), 8B aligned
#define NSCAN_BLOCKS 215    // ceil(220000 / 1024)
#define SME_CAP 384         // max edges per (rel, 32-node tile); lambda~93, 30 sigma
#define FB   2969           // k_prep blocks: feat convert (760000 uint4 / 256)
#define WB   44             // k_prep blocks: wt tiles (11 r x 4 o-tiles)
#define HB   215            // k_prep blocks: hist zero (215*1024)

typedef short bf16x8 __attribute__((ext_vector_type(8)));
typedef float f32x16 __attribute__((ext_vector_type(16)));

union UA { bf16x8 v; uint2 d[2]; };
union UB { bf16x8 v; uint4 q; };

__device__ inline unsigned short f2bf(float f) {
    union { float f; unsigned u; } x;
    x.f = f;
    unsigned u = x.u;
    u += 0x7fffu + ((u >> 16) & 1u);   // round-to-nearest-even
    return (unsigned short)(u >> 16);
}
__device__ inline float bflo(unsigned p) { return __uint_as_float(p << 16); }
__device__ inline float bfhi(unsigned p) { return __uint_as_float(p & 0xFFFF0000u); }
__device__ inline unsigned packbf(float x, float y) {
    return (unsigned)f2bf(x) | ((unsigned)f2bf(y) << 16);
}

// ---- fused prep: feat->bf16 padded rows | wt LDS-transpose tiles | hist zero
__global__ __launch_bounds__(256) void k_prep(const float* __restrict__ feat,
                                              const float* __restrict__ comps,
                                              const float* __restrict__ bases,
                                              unsigned* __restrict__ f2u,
                                              unsigned short* __restrict__ wt,
                                              unsigned* __restrict__ hist) {
    __shared__ unsigned short ld[KP * 65];   // wt tile (k x o), pad 65 -> conflict-free
    const int b = blockIdx.x, tid = threadIdx.x;

    if (b < FB) {
        // feat2[d][0..151] uints (304 bf16, k>=300 zero). 38 uint4 per row.
        const unsigned t = b * 256u + (unsigned)tid;
        if (t < 760000u) {
            const unsigned d = t / 38u, c4 = t - d * 38u, k0 = c4 * 8u;
            const float* fp = feat + (size_t)d * IND + k0;
            float v4 = 0.f, v5 = 0.f, v6 = 0.f, v7 = 0.f;
            const float4 x = *(const float4*)fp;
            if (k0 + 4 < (unsigned)IND) {
                const float4 y = *(const float4*)(fp + 4);
                v4 = y.x; v5 = y.y; v6 = y.z; v7 = y.w;
            }
            uint4 o;
            o.x = packbf(x.x, x.y); o.y = packbf(x.z, x.w);
            o.z = packbf(v4, v5);   o.w = packbf(v6, v7);
            *(uint4*)(f2u + (size_t)t * 4u) = o;
        }
        return;
    }
    if (b < FB + WB) {
        // wt[r][o][k] bf16: coalesced bases reads, LDS transpose, coalesced writes
        const int w  = b - FB;               // 0..43
        const int r  = w >> 2, o0 = (w & 3) * 64;
        const int o4 = tid & 63, kq = tid >> 6;     // kq 0..3
        float cw[BB];
#pragma unroll
        for (int bb = 0; bb < BB; ++bb) cw[bb] = comps[r * BB + bb];
        for (int ks = 0; ks < 76; ++ks) {
            const int k = ks * 4 + kq;
            float acc = 0.f;
            if (k < IND) {
#pragma unroll
                for (int bb = 0; bb < BB; ++bb)
                    acc += cw[bb] * bases[((size_t)bb * IND + k) * OUTD + o0 + o4];
            }
            ld[k * 65 + o4] = f2bf(acc);
        }
        __syncthreads();
        unsigned* wtu = (unsigned*)wt;
        for (int j = tid; j < 64 * KPU; j += 256) {
            const int oo = j / KPU, ku = j - oo * KPU;
            const unsigned lo = ld[(2 * ku) * 65 + oo];
            const unsigned hi = ld[(2 * ku + 1) * 65 + oo];
            wtu[((size_t)(r * OUTD + o0 + oo)) * KPU + ku] = lo | (hi << 16);
        }
        return;
    }
    // hist zero
    const unsigned base = (unsigned)(b - FB - WB) * 1024u + (unsigned)tid;
#pragma unroll
    for (int i = 0; i < 4; ++i) {
        const unsigned idx = base + i * 256u;
        if (idx < RN) hist[idx] = 0u;
    }
}

// ---------------------------------------------------------------- histogram
__global__ __launch_bounds__(256) void k_hist(const int* __restrict__ esrc,
                                              const int* __restrict__ erel,
                                              unsigned* __restrict__ hist) {
    const int e = blockIdx.x * 256 + threadIdx.x;           // exactly 640000
    const unsigned key = (unsigned)erel[e] * NN + (unsigned)esrc[e];
    atomicAdd(&hist[key], 1u);
}

// ------------------------------------------------- scan level 1 (1024/block)
__global__ __launch_bounds__(256) void k_scan1(const unsigned* __restrict__ hist,
                                               unsigned* __restrict__ off,
                                               unsigned* __restrict__ bsum) {
    __shared__ unsigned sc[256];
    const int tid = threadIdx.x;
    const unsigned base = blockIdx.x * 1024u + (unsigned)tid * 4u;
    unsigned v0 = (base + 0 < RN) ? hist[base + 0] : 0u;
    unsigned v1 = (base + 1 < RN) ? hist[base + 1] : 0u;
    unsigned v2 = (base + 2 < RN) ? hist[base + 2] : 0u;
    unsigned v3 = (base + 3 < RN) ? hist[base + 3] : 0u;
    const unsigned s = v0 + v1 + v2 + v3;
    sc[tid] = s;
    __syncthreads();
    for (int d = 1; d < 256; d <<= 1) {
        unsigned t = (tid >= d) ? sc[tid - d] : 0u;
        __syncthreads();
        sc[tid] += t;
        __syncthreads();
    }
    if (tid == 255) bsum[blockIdx.x] = sc[255];
    unsigned run = sc[tid] - s;                              // exclusive
    if (base + 0 < RN) off[base + 0] = run; run += v0;
    if (base + 1 < RN) off[base + 1] = run; run += v1;
    if (base + 2 < RN) off[base + 2] = run; run += v2;
    if (base + 3 < RN) off[base + 3] = run;
}

// ------------- scan levels 2+3 fused: every block re-scans bsum (tiny, L2)
__global__ __launch_bounds__(256) void k_scan23(unsigned* __restrict__ off,
                                                unsigned* __restrict__ off2,
                                                const unsigned* __restrict__ bsum) {
    __shared__ unsigned sb[256];
    const int tid = threadIdx.x;
    if (tid < 64) {
        unsigned v[4]; unsigned tot = 0;
#pragma unroll
        for (int i = 0; i < 4; ++i) {
            const int idx = tid * 4 + i;
            v[i] = (idx < NSCAN_BLOCKS) ? bsum[idx] : 0u;
            tot += v[i];
        }
        unsigned sc = tot;
        for (int d = 1; d < 64; d <<= 1) {
            unsigned t = __shfl_up(sc, d, 64);
            if (tid >= d) sc += t;
        }
        unsigned run = sc - tot;
#pragma unroll
        for (int i = 0; i < 4; ++i) {
            sb[tid * 4 + i] = run;
            run += v[i];
        }
    }
    __syncthreads();
    const unsigned idx = blockIdx.x * 256u + (unsigned)tid;
    if (idx < RN) {
        const unsigned v = off[idx] + sb[idx >> 10];
        off[idx]  = v;
        off2[idx] = v;
    }
    if (idx == 0) off[RN] = EE;
}

// ------------------------------------------------------- counting-sort scatter
__global__ __launch_bounds__(256) void k_scatter(const int* __restrict__ esrc,
                                                 const int* __restrict__ erel,
                                                 const int* __restrict__ edst,
                                                 unsigned* __restrict__ off2,
                                                 unsigned* __restrict__ ssd) {
    const int e = blockIdx.x * 256 + threadIdx.x;           // exactly 640000
    const unsigned key = (unsigned)erel[e] * NN + (unsigned)esrc[e];
    const unsigned p = atomicAdd(&off2[key], 1u);
    ssd[p] = (unsigned)edst[e];                              // dst only; src = bucket
}

// ---------------------------------------------------------------- fused main
// SPLIT=1: grid 1250, block = (32-node tile) x (rel-half); half0 rels 0..5 -> P,
// half1 rels 6..10 -> out; k_add sums + bias. SPLIT=0: grid 625, all rels -> out.
// Gather: lane l<38 owns k=8l..8l+7 (one uint4/edge), depth-2 software prefetch,
// accumulates 8 fp32 regs, packs + stores its own sbf fragment. No LDS atomics.
template<int SPLIT>
__global__ __launch_bounds__(512, 8) void k_main(const unsigned* __restrict__ f2u,
                                                 const float* __restrict__ bias,
                                                 const unsigned* __restrict__ offs,
                                                 const unsigned* __restrict__ ssd,
                                                 const unsigned short* __restrict__ wt,
                                                 float* __restrict__ out,
                                                 float* __restrict__ P) {
    __shared__ unsigned short sbf[32 * SBS];
    __shared__ unsigned sme[SME_CAP];
    __shared__ unsigned soffs[RR * 33];

    const int tid  = threadIdx.x;
    const int wave = tid >> 6;
    const int lane = tid & 63;
    const int row  = lane & 31;
    const int q    = lane >> 5;

    int tile, half, r0, r1;
    if (SPLIT) {
        tile = blockIdx.x >> 1; half = blockIdx.x & 1;
        r0 = half ? 6 : 0; r1 = half ? 11 : 6;
    } else {
        tile = blockIdx.x; half = 0; r0 = 0; r1 = RR;
    }
    const int n0 = tile * 32;
    const int o0 = wave * 32;

    if (tid < RR * 33) {
        const int r = tid / 33, j = tid - r * 33;
        soffs[tid] = offs[r * NN + n0 + j];
    }

    f32x16 acc;
#pragma unroll
    for (int i = 0; i < 16; ++i) acc[i] = 0.f;

    const unsigned cl = (unsigned)(lane < 38 ? lane : 37) * 4u;   // uint col offset

    __syncthreads();

    for (int r = r0; r < r1; ++r) {
        const unsigned* so = soffs + r * 33;
        const unsigned e0v = so[0];
        const unsigned nE  = min(so[32] - e0v, (unsigned)SME_CAP);
        for (unsigned j = (unsigned)tid; j < nE; j += 512u)
            sme[j] = ssd[e0v + j];
        __syncthreads();

#pragma unroll
        for (int g = 0; g < 4; ++g) {
            const int m = wave * 4 + g;
            const unsigned c0 = min(so[m] - e0v, nE);
            const unsigned c1 = min(so[m + 1] - e0v, nE);
            const unsigned cnt = c1 - c0;
            float a0 = 0, a1 = 0, a2 = 0, a3 = 0, a4 = 0, a5 = 0, a6 = 0, a7 = 0;
            uint4 f0, f1;
            if (cnt > 0) f0 = *(const uint4*)(f2u + (size_t)sme[c0] * KPU + cl);
            if (cnt > 1) f1 = *(const uint4*)(f2u + (size_t)sme[c0 + 1] * KPU + cl);
            for (unsigned e = 0; e < cnt; ++e) {
                const uint4 cur = f0;
                f0 = f1;
                if (e + 2 < cnt)
                    f1 = *(const uint4*)(f2u + (size_t)sme[c0 + e + 2] * KPU + cl);
                a0 += bflo(cur.x); a1 += bfhi(cur.x);
                a2 += bflo(cur.y); a3 += bfhi(cur.y);
                a4 += bflo(cur.z); a5 += bfhi(cur.z);
                a6 += bflo(cur.w); a7 += bfhi(cur.w);
            }
            const float inv = cnt ? 1.0f / (float)cnt : 0.f;
            if (lane < 38) {
                uint2 w0, w1;
                w0.x = packbf(a0 * inv, a1 * inv);
                w0.y = packbf(a2 * inv, a3 * inv);
                w1.x = packbf(a4 * inv, a5 * inv);
                w1.y = packbf(a6 * inv, a7 * inv);
                *(uint2*)(sbf + m * SBS + 8 * lane)     = w0;
                *(uint2*)(sbf + m * SBS + 8 * lane + 4) = w1;
            }
        }
        __syncthreads();

        // --- MFMA: C[32 nodes x 32 outs] += A[32 x 304] * B[304 x 32]
        const unsigned short* wb = wt + ((size_t)(r * OUTD + o0 + row) * KP) + 8 * q;
        const unsigned short* ab = sbf + row * SBS + 8 * q;
#pragma unroll
        for (int ks = 0; ks < 19; ++ks) {
            UA a; UB b;
            a.d[0] = *(const uint2*)(ab + 16 * ks);
            a.d[1] = *(const uint2*)(ab + 16 * ks + 4);
            b.q    = *(const uint4*)(wb + 16 * ks);
            acc = __builtin_amdgcn_mfma_f32_32x32x16_bf16(a.v, b.v, acc, 0, 0, 0);
        }
        // next sme write is behind this wave's MFMA; sbf writes behind a barrier
    }

    // --- epilogue: C/D layout col=lane&31 (=o), row=(reg&3)+8*(reg>>2)+4*q (=node)
    float* ob = SPLIT ? (half ? out : P) : out;
    const int o = o0 + row;
    const float bv = SPLIT ? 0.f : bias[o];
#pragma unroll
    for (int reg = 0; reg < 16; ++reg) {
        const int node = (reg & 3) + 8 * (reg >> 2) + 4 * q;
        ob[(size_t)(n0 + node) * OUTD + o] = acc[reg] + bv;
    }
}

// --------------------------- out = out + P + bias (SPLIT path only)
__global__ __launch_bounds__(256) void k_add(float* __restrict__ out,
                                             const float* __restrict__ P,
                                             const float* __restrict__ bias) {
    const unsigned i = blockIdx.x * 256u + threadIdx.x;     // 1,280,000 float4
    float4 o = ((float4*)out)[i];
    const float4 p  = ((const float4*)P)[i];
    const float4 bv = ((const float4*)bias)[i & 63u];
    o.x += p.x + bv.x; o.y += p.y + bv.y;
    o.z += p.z + bv.z; o.w += p.w + bv.w;
    ((float4*)out)[i] = o;
}

extern "C" void kernel_launch(void* const* d_in, const int* in_sizes, int n_in,
                              void* d_out, int out_size, void* d_ws, size_t ws_size,
                              hipStream_t stream) {
    const float* feat  = (const float*)d_in[0];
    const float* comps = (const float*)d_in[1];
    const float* bases = (const float*)d_in[2];
    const float* bias  = (const float*)d_in[3];
    const int*   esrc  = (const int*)d_in[4];
    const int*   erel  = (const int*)d_in[5];
    const int*   edst  = (const int*)d_in[6];
    float* out = (float*)d_out;

    char* ws = (char*)d_ws;
    // ws layout (bytes):
    unsigned short* wt   = (unsigned short*)(ws + 0);        //  1,712,128
    unsigned*       hist = (unsigned*)(ws + 1712128);        //    880,000
    unsigned*       off  = (unsigned*)(ws + 2592128);        //    880,064 (incl pad)
    unsigned*       off2 = (unsigned*)(ws + 3472192);        //    880,000
    unsigned*       bsum = (unsigned*)(ws + 4352192);        //      1,024
    unsigned*       ssd  = (unsigned*)(ws + 4353216);        //  2,560,000
    unsigned*       f2u  = (unsigned*)(ws + 6913216);        // 12,160,000 -> 19,073,216
    float*          P    = (float*)(ws + 19073216);          // 20,480,000 -> 39,553,216

    // host-uniform gates (constant across calls)
    const bool split = ws_size >= (size_t)39553216;

    hipLaunchKernelGGL(k_prep,    dim3(FB + WB + HB), dim3(256), 0, stream,
                       feat, comps, bases, f2u, wt, hist);
    hipLaunchKernelGGL(k_hist,    dim3(2500), dim3(256), 0, stream, esrc, erel, hist);
    hipLaunchKernelGGL(k_scan1,   dim3(NSCAN_BLOCKS), dim3(256), 0, stream, hist, off, bsum);
    hipLaunchKernelGGL(k_scan23,  dim3(860),  dim3(256), 0, stream, off, off2, bsum);
    hipLaunchKernelGGL(k_scatter, dim3(2500), dim3(256), 0, stream, esrc, erel, edst, off2, ssd);
    if (split) {
        hipLaunchKernelGGL((k_main<1>), dim3(1250), dim3(512), 0, stream,
                           f2u, bias, off, ssd, wt, out, P);
        hipLaunchKernelGGL(k_add, dim3(5000), dim3(256), 0, stream, out, P, bias);
    } else {
        hipLaunchKernelGGL((k_main<0>), dim3(625), dim3(512), 0, stream,
                           f2u, bias, off, ssd, wt, out, P);
    }

    (void)in_sizes; (void)n_in; (void)out_size; (void)ws_size;
}